// Round 4
// baseline (472.858 us; speedup 1.0000x reference)
//
#include <hip/hip_runtime.h>
#include <math.h>

#define ROW_N 2048
#define KSEL 10
#define WCAP 64   // per-wave candidate cap
#define RPW  4    // rows per wave (software pipeline depth source)

typedef float f32x4 __attribute__((ext_vector_type(4)));
typedef unsigned long long u64;

// Wave-per-row, 4 rows per wave, double-buffered registers (A/B):
// the next row's 8 global loads are issued BEFORE the current row's compute,
// so HBM latency hides under ~2000 cycles of per-row work and the memory
// pipe is continuously fed (fixes the additive load->compute->store phasing
// seen at ~160us / 2.6 TB/s).
//
// Per row: stats (mu/sig/max butterflies) -> collect exact candidate keys
// (ord(v)<<16 | (2047-idx), raw v bits => exact lax.top_k tie-break) into a
// wave-private LDS slice via ballot+mbcnt -> exp overwrites v IN-REGISTER
// (single exp per element, accumulates tot) -> 48-bit ballot binary search
// for the 10th-largest key kmin -> output = e * (0.1/rem), nt-stored ->
// in-wave s_waitcnt vmcnt(0) -> the <=10 winner lanes patch their positions
// with 0.9*softmax(top10). No __syncthreads anywhere.
__global__ __launch_bounds__(256) void topk_softmax_kernel(
    const float* __restrict__ in, float* __restrict__ out, int nw)
{
    const int lane = threadIdx.x & 63;
    const int wave = threadIdx.x >> 6;
    const int wid  = blockIdx.x * 4 + wave;

    __shared__ u64 s_cand[4][WCAP];   // 2 KB, wave-private slices

    f32x4 A[8], B[8];

    auto loadrow = [&](f32x4 (&V)[8], int row) {
        const f32x4* p = reinterpret_cast<const f32x4*>(in + (size_t)row * ROW_N);
        #pragma unroll
        for (int j = 0; j < 8; ++j) V[j] = p[j * 64 + lane];
    };

    auto process = [&](f32x4 (&V)[8], int row) {
        const size_t rbase = (size_t)row * ROW_N;

        // fused row stats: sum, sumsq, max (one pass, 3 butterflies)
        float s = 0.f, q = 0.f, vm = -INFINITY;
        #pragma unroll
        for (int j = 0; j < 8; ++j)
            #pragma unroll
            for (int c = 0; c < 4; ++c) {
                float x = V[j][c];
                s += x; q = fmaf(x, x, q); vm = fmaxf(vm, x);
            }
        #pragma unroll
        for (int off = 32; off > 0; off >>= 1) {
            s += __shfl_xor(s, off);
            q += __shfl_xor(q, off);
            vm = fmaxf(vm, __shfl_xor(vm, off));
        }
        const float mu    = s * (1.f / ROW_N);
        const float sig   = sqrtf(fmaxf(q * (1.f / ROW_N) - mu * mu, 1e-20f));
        const float shift = fmaf(4.f, sig, mu);   // exp frame for remaining mass
        float Tf = fmaf(2.2f, sig, mu);           // candidate threshold (~29 hits)

        // collect candidates (exact raw-v keys) BEFORE exp overwrites V.
        // ballot+mbcnt compaction, count uniform from popcounts; rare
        // wave-local retry if count drifts out of [10, 64].
        int C = 0;
        #pragma unroll 1
        for (int t = 0; t < 8; ++t) {
            C = 0;
            #pragma unroll
            for (int j = 0; j < 8; ++j)
                #pragma unroll
                for (int c = 0; c < 4; ++c) {
                    bool cond = V[j][c] > Tf;
                    u64 m = __ballot(cond);
                    if (cond) {
                        int idx = j * 256 + lane * 4 + c;
                        uint32_t u  = __float_as_uint(V[j][c]);
                        uint32_t ov = u ^ ((uint32_t)((int32_t)u >> 31) | 0x80000000u);
                        int pos = C + (int)__builtin_amdgcn_mbcnt_hi(
                                          (unsigned)(m >> 32),
                                          __builtin_amdgcn_mbcnt_lo((unsigned)m, 0u));
                        if (pos < WCAP)
                            s_cand[wave][pos] = ((u64)ov << 16) |
                                                (unsigned)(2047 - idx);
                    }
                    C += __popcll(m);
                }
            if (C >= KSEL && C <= WCAP) break;
            Tf += (C < KSEL) ? (-0.5f * sig) : (0.5f * sig);
        }
        if (C > WCAP) C = WCAP;

        u64 k0 = (lane < C) ? s_cand[wave][lane] : 0ULL;   // in-wave LDS, no barrier

        // single exp pass, overwrite V in place; accumulate total mass
        float tot = 0.f;
        #pragma unroll
        for (int j = 0; j < 8; ++j) {
            f32x4 e;
            #pragma unroll
            for (int c = 0; c < 4; ++c) { e[c] = __expf(V[j][c] - shift); tot += e[c]; }
            V[j] = e;
        }
        #pragma unroll
        for (int off = 32; off > 0; off >>= 1) tot += __shfl_xor(tot, off);

        // exact 10th-largest key via 48-bit ballot binary search (mostly SALU)
        u64 kmin = 0ULL;
        #pragma unroll 1
        for (int b = 47; b >= 0; --b) {
            u64 trial = kmin | (1ULL << b);
            u64 mm = __ballot(k0 >= trial);
            if (__popcll(mm) >= KSEL) kmin = trial;
        }

        // top-10 softmax mass (exactly the 10 lanes with k0 >= kmin; kmin>0
        // excludes the k0==0 filler lanes)
        uint32_t ovk = (uint32_t)(k0 >> 16);
        float val = __uint_as_float(ovk ^ ((ovk & 0x80000000u) ? 0x80000000u
                                                              : 0xFFFFFFFFu));
        const bool win = (lane < C) && (k0 >= kmin);
        float ee = win ? __expf(val - vm) : 0.f;
        float ssum = ee;
        #pragma unroll
        for (int off = 32; off > 0; off >>= 1) ssum += __shfl_xor(ssum, off);

        const float tsum = ssum * __expf(vm - shift);   // top-10 mass, shift frame
        const float aa   = 0.9f / ssum;
        const float bb   = 0.1f / (tot - tsum);

        // bulk output: e * bb everywhere (winners fixed by patch below)
        f32x4* o4 = reinterpret_cast<f32x4*>(out + rbase);
        #pragma unroll
        for (int j = 0; j < 8; ++j) {
            f32x4 o;
            #pragma unroll
            for (int c = 0; c < 4; ++c) o[c] = V[j][c] * bb;
            __builtin_nontemporal_store(o, o4 + j * 64 + lane);
        }

        // wave owns the whole row: draining this wave's stores suffices.
        // (Older prefetch loads completed during compute; no extra stall.)
        asm volatile("s_waitcnt vmcnt(0)" ::: "memory");
        if (win) out[rbase + (2047 - (int)(k0 & 0xFFFFull))] = ee * aa;
    };

    loadrow(A, wid);                               // prologue
    #pragma unroll 1
    for (int r = 0; r < RPW; r += 2) {
        loadrow(B, wid + (r + 1) * nw);            // prefetch before compute
        process(A, wid + r * nw);
        if (r + 2 < RPW) loadrow(A, wid + (r + 2) * nw);
        process(B, wid + (r + 1) * nw);
    }
}

extern "C" void kernel_launch(void* const* d_in, const int* in_sizes, int n_in,
                              void* d_out, int out_size, void* d_ws, size_t ws_size,
                              hipStream_t stream) {
    const float* logits = (const float*)d_in[0];
    float* out = (float*)d_out;
    const int rows = out_size / ROW_N;    // 2*8*2048 = 32768
    const int nw = rows / RPW;            // 8192 waves
    topk_softmax_kernel<<<dim3(nw / 4), dim3(256), 0, stream>>>(logits, out, nw);
}